// Round 7
// baseline (29.328 us; speedup 1.0000x reference)
//
#include <hip/hip_runtime.h>
#include <climits>

// B=256 rows, N=65536, half=32768.
constexpr int HALF  = 32768;
constexpr int TPB   = 256;
constexpr int CHUNK = 2048;              // elements per half-stream per block
constexpr int NCHNK = HALF / CHUNK;      // 16 chunks per row
constexpr float THRESH = 0.01f;

// ---------------- Kernel A: streaming pass, 8 float4s FORCED in flight ----------------
__global__ __launch_bounds__(TPB)
void main_kernel(const float* __restrict__ pred, const float* __restrict__ label,
                 float* __restrict__ part_sum, int4* __restrict__ part_idx)
{
    const int chunk = blockIdx.x, row = blockIdx.y;
    const int t = threadIdx.x, wave = t >> 6, lane = t & 63;

    const size_t rb4 = (size_t)row * (size_t)(2 * HALF / 4);
    const float4* lr4 = (const float4*)label + rb4;
    const float4* pr4 = (const float4*)pred + rb4;

    const int v0 = chunk * (CHUNK / 4) + t;          // coalesced: lane l -> float4 l
    const int v1 = v0 + TPB;
    const int H4 = HALF / 4;

    // all 8 independent loads issued upfront
    float4 a0 = lr4[v0],      a1 = lr4[v1];
    float4 b0 = lr4[v0 + H4], b1 = lr4[v1 + H4];
    float4 p0 = pr4[v0],      p1 = pr4[v1];
    float4 q0 = pr4[v0 + H4], q1 = pr4[v1 + H4];

    // Optimization barrier: every loaded component is an in/out operand, so ALL
    // 8 global loads must be issued+completed before ANY compute below. This
    // stops the compiler from serializing loads to save registers (R6: VGPR=24
    // proved it issued 4, waited, computed, issued 4).
    asm volatile("" :
        "+v"(a0.x), "+v"(a0.y), "+v"(a0.z), "+v"(a0.w),
        "+v"(a1.x), "+v"(a1.y), "+v"(a1.z), "+v"(a1.w),
        "+v"(b0.x), "+v"(b0.y), "+v"(b0.z), "+v"(b0.w),
        "+v"(b1.x), "+v"(b1.y), "+v"(b1.z), "+v"(b1.w),
        "+v"(p0.x), "+v"(p0.y), "+v"(p0.z), "+v"(p0.w),
        "+v"(p1.x), "+v"(p1.y), "+v"(p1.z), "+v"(p1.w),
        "+v"(q0.x), "+v"(q0.y), "+v"(q0.z), "+v"(q0.w),
        "+v"(q1.x), "+v"(q1.y), "+v"(q1.z), "+v"(q1.w));

    float sum = 0.f;
    int minr = INT_MAX, maxr = -1, mini = INT_MAX, maxi = -1;

#define STEP(ax, bx, px, qx, idx)                                 \
    {                                                             \
        float dr = (px) - (ax), di = (qx) - (bx);                 \
        float lint = (ax) * (ax) + (bx) * (bx);                   \
        float pint = (px) * (px) + (qx) * (qx);                   \
        float dd = pint - lint;                                   \
        sum += dr * dr + di * di + 50.f * dd * dd;                \
        if (fabsf(ax) > THRESH) {                                 \
            minr = min(minr, (idx)); maxr = max(maxr, (idx));     \
        }                                                         \
        if (fabsf(bx) > THRESH) {                                 \
            mini = min(mini, (idx)); maxi = max(maxi, (idx));     \
        }                                                         \
    }
    {
        const int base = v0 * 4;
        STEP(a0.x, b0.x, p0.x, q0.x, base + 0)
        STEP(a0.y, b0.y, p0.y, q0.y, base + 1)
        STEP(a0.z, b0.z, p0.z, q0.z, base + 2)
        STEP(a0.w, b0.w, p0.w, q0.w, base + 3)
    }
    {
        const int base = v1 * 4;
        STEP(a1.x, b1.x, p1.x, q1.x, base + 0)
        STEP(a1.y, b1.y, p1.y, q1.y, base + 1)
        STEP(a1.z, b1.z, p1.z, q1.z, base + 2)
        STEP(a1.w, b1.w, p1.w, q1.w, base + 3)
    }
#undef STEP

    // unordered wave reduce
    #pragma unroll
    for (int off = 32; off > 0; off >>= 1) {
        sum += __shfl_down(sum, off);
        minr = min(minr, __shfl_down(minr, off));
        maxr = max(maxr, __shfl_down(maxr, off));
        mini = min(mini, __shfl_down(mini, off));
        maxi = max(maxi, __shfl_down(maxi, off));
    }

    __shared__ float s_sum[4];
    __shared__ int   s_idx[4][4];
    if (lane == 0) {
        s_sum[wave] = sum;
        s_idx[wave][0] = minr; s_idx[wave][1] = maxr;
        s_idx[wave][2] = mini; s_idx[wave][3] = maxi;
    }
    __syncthreads();
    if (t == 0) {
        float S = 0.f; int mr = INT_MAX, Mr = -1, mi = INT_MAX, Mi = -1;
        #pragma unroll
        for (int w = 0; w < 4; ++w) {
            S += s_sum[w];
            mr = min(mr, s_idx[w][0]); Mr = max(Mr, s_idx[w][1]);
            mi = min(mi, s_idx[w][2]); Mi = max(Mi, s_idx[w][3]);
        }
        const int slot = row * NCHNK + chunk;        // [row][chunk]
        part_sum[slot] = S;
        part_idx[slot] = make_int4(mr, Mr, mi, Mi);
    }
}

// ---------------- Kernel B: per-row edges + total (256 blocks, parallel) ----------------
__global__ __launch_bounds__(TPB)
void edge_kernel(const float* __restrict__ pred, const float* __restrict__ label,
                 const float* __restrict__ part_sum, const int4* __restrict__ part_idx,
                 float* __restrict__ row_tot)
{
    const int row = blockIdx.x;
    const int t = threadIdx.x, wave = t >> 6, lane = t & 63;

    float base = 0.f;
    int fr = INT_MAX, lastr = -1, fi = INT_MAX, lasti = -1;
    #pragma unroll
    for (int s = 0; s < NCHNK; ++s) {
        base += part_sum[row * NCHNK + s];
        int4 v = part_idx[row * NCHNK + s];
        fr = min(fr, v.x); lastr = max(lastr, v.y);
        fi = min(fi, v.z); lasti = max(lasti, v.w);
    }
    if (lastr < 0) { fr = 0; lastr = HALF - 1; }
    if (lasti < 0) { fi = 0; lasti = HALF - 1; }

    const float* Lr = label + (size_t)row * (2 * HALF);
    const float* Li = Lr + HALF;
    const float* Pr = pred + (size_t)row * (2 * HALF);
    const float* Pi = Pr + HALF;

    // extra +1*d^2 outside [first,last] (typically ~0-2 elements per edge)
    float ex = 0.f;
    for (int i = t; i < fr; i += TPB)               { float d = Pr[i] - Lr[i]; ex += d * d; }
    for (int i = lastr + 1 + t; i < HALF; i += TPB) { float d = Pr[i] - Lr[i]; ex += d * d; }
    for (int i = t; i < fi; i += TPB)               { float d = Pi[i] - Li[i]; ex += d * d; }
    for (int i = lasti + 1 + t; i < HALF; i += TPB) { float d = Pi[i] - Li[i]; ex += d * d; }

    #pragma unroll
    for (int off = 32; off > 0; off >>= 1) ex += __shfl_down(ex, off);
    __shared__ float s_ex[4];
    if (lane == 0) s_ex[wave] = ex;
    __syncthreads();
    if (t == 0)
        row_tot[row] = base + s_ex[0] + s_ex[1] + s_ex[2] + s_ex[3];
}

// ---------------- Kernel C: final deterministic reduce ----------------
__global__ void finalize_kernel(const float* __restrict__ row_tot,
                                float* __restrict__ out, int rows)
{
    const int t = threadIdx.x;   // 256 threads, 1 block
    float v = 0.f;
    for (int i = t; i < rows; i += 256) v += row_tot[i];
    #pragma unroll
    for (int off = 32; off > 0; off >>= 1) v += __shfl_down(v, off);
    __shared__ float s[4];
    if ((t & 63) == 0) s[t >> 6] = v;
    __syncthreads();
    if (t == 0)
        out[0] = (s[0] + s[1] + s[2] + s[3]) * (1.0f / ((float)HALF * (float)rows));
}

extern "C" void kernel_launch(void* const* d_in, const int* in_sizes, int n_in,
                              void* d_out, int out_size, void* d_ws, size_t ws_size,
                              hipStream_t stream) {
    const float* pred  = (const float*)d_in[0];
    const float* label = (const float*)d_in[1];
    float* out = (float*)d_out;

    const int rows = in_sizes[0] / (2 * HALF);   // 256
    const int nslots = rows * NCHNK;             // 4096

    float* part_sum = (float*)d_ws;                          // 4096 floats = 16 KB
    int4*  part_idx = (int4*)((char*)d_ws + nslots * 4);     // 64 KB, 16B-aligned
    float* row_tot  = (float*)((char*)d_ws + nslots * 4 + nslots * 16);

    dim3 gridA(NCHNK, rows);
    main_kernel<<<gridA, TPB, 0, stream>>>(pred, label, part_sum, part_idx);
    edge_kernel<<<rows, TPB, 0, stream>>>(pred, label, part_sum, part_idx, row_tot);
    finalize_kernel<<<1, 256, 0, stream>>>(row_tot, out, rows);
}